// Round 1
// baseline (1921.849 us; speedup 1.0000x reference)
//
#include <hip/hip_runtime.h>
#include <math.h>

#define NN 4096
#define NE 131072

__device__ __forceinline__ float lrelu_f(float x) { return x > 0.0f ? x : 0.01f * x; }

// ---------------- GEMM: O[M,P] = act(A)[M,K] @ W[K,P] + b ----------------
template<bool RELU_A>
__global__ __launch_bounds__(256) void gemm_kernel(const float* __restrict__ A,
    const float* __restrict__ W, const float* __restrict__ bias,
    float* __restrict__ O, int K, int P) {
  __shared__ float As[64][33];
  __shared__ float Ws[32][65];
  int i0 = blockIdx.x * 64, n0 = blockIdx.y * 64;
  int t = threadIdx.x, ty = t >> 4, tx = t & 15;
  float acc[4][4] = {};
  for (int k0 = 0; k0 < K; k0 += 32) {
    __syncthreads();
    for (int idx = t; idx < 64 * 32; idx += 256) {
      int r = idx >> 5, k = idx & 31;
      float v = A[(size_t)(i0 + r) * K + k0 + k];
      if (RELU_A) v = fmaxf(v, 0.0f);
      As[r][k] = v;
    }
    for (int idx = t; idx < 32 * 64; idx += 256) {
      int k = idx >> 6, n = idx & 63;
      Ws[k][n] = W[(size_t)(k0 + k) * P + n0 + n];
    }
    __syncthreads();
    for (int k = 0; k < 32; ++k) {
      float a[4], b[4];
      #pragma unroll
      for (int q = 0; q < 4; ++q) a[q] = As[4 * ty + q][k];
      #pragma unroll
      for (int p = 0; p < 4; ++p) b[p] = Ws[k][4 * tx + p];
      #pragma unroll
      for (int q = 0; q < 4; ++q)
        #pragma unroll
        for (int p = 0; p < 4; ++p) acc[q][p] = fmaf(a[q], b[p], acc[q][p]);
    }
  }
  #pragma unroll
  for (int q = 0; q < 4; ++q)
    #pragma unroll
    for (int p = 0; p < 4; ++p)
      O[(size_t)(i0 + 4 * ty + q) * P + n0 + 4 * tx + p] = acc[q][p] + bias[n0 + 4 * tx + p];
}

// ---------------- row stats: inv_norm, al, ar ----------------
template<int DH>
__global__ __launch_bounds__(256) void rowstats_kernel(const float* __restrict__ h,
    const float* __restrict__ aw, float* __restrict__ al, float* __restrict__ ar,
    float* __restrict__ inv) {
  constexpr int NC = DH / 64;
  int wid = threadIdx.x >> 6, lane = threadIdx.x & 63;
  int i = blockIdx.x * 4 + wid;
  float s2 = 0.f, sl = 0.f, sr = 0.f;
  #pragma unroll
  for (int c = 0; c < NC; ++c) {
    float x = h[(size_t)i * DH + c * 64 + lane];
    s2 = fmaf(x, x, s2);
    sl = fmaf(x, aw[c * 64 + lane], sl);
    sr = fmaf(x, aw[DH + c * 64 + lane], sr);
  }
  #pragma unroll
  for (int m = 32; m > 0; m >>= 1) {
    s2 += __shfl_xor(s2, m);
    sl += __shfl_xor(sl, m);
    sr += __shfl_xor(sr, m);
  }
  if (lane == 0) { al[i] = sl; ar[i] = sr; inv[i] = rsqrtf(s2); }
}

// ---------------- column sum ----------------
template<int DH>
__global__ void colsum_kernel(const float* __restrict__ h, float* __restrict__ cs) {
  int d = threadIdx.x;             // blockDim == DH
  int r0 = blockIdx.x * (NN / 32);
  float s = 0.f;
  for (int i = 0; i < NN / 32; ++i) s += h[(size_t)(r0 + i) * DH + d];
  atomicAdd(&cs[d], s);
}

// ---------------- CSR build ----------------
__global__ void hist_kernel(const int* __restrict__ src, int* __restrict__ counts) {
  int e = blockIdx.x * 256 + threadIdx.x;
  atomicAdd(&counts[src[e]], 1);
}

__global__ __launch_bounds__(1024) void scan_kernel(const int* __restrict__ counts,
    int* __restrict__ offsets, int* __restrict__ cursor) {
  __shared__ int part[1024];
  int t = threadIdx.x;
  int v[4]; int run = 0;
  #pragma unroll
  for (int j = 0; j < 4; ++j) { v[j] = counts[4 * t + j]; run += v[j]; }
  part[t] = run;
  __syncthreads();
  for (int off = 1; off < 1024; off <<= 1) {
    int y = (t >= off) ? part[t - off] : 0;
    __syncthreads();
    part[t] += y;
    __syncthreads();
  }
  int base = part[t] - run;
  #pragma unroll
  for (int j = 0; j < 4; ++j) { offsets[4 * t + j] = base; cursor[4 * t + j] = base; base += v[j]; }
  if (t == 1023) offsets[NN] = base;
}

__global__ void scatter_kernel(const int* __restrict__ src, const int* __restrict__ dst,
    const float* __restrict__ al, const float* __restrict__ ar, const float* __restrict__ ab,
    float* __restrict__ denom, int* __restrict__ cursor,
    int* __restrict__ dstS, float* __restrict__ eS) {
  int e = blockIdx.x * 256 + threadIdx.x;
  int s = src[e], d = dst[e];
  float v = expf(lrelu_f(al[s] + ar[d] + ab[0]));
  atomicAdd(&denom[s], v);
  int p = atomicAdd(&cursor[s], 1);
  dstS[p] = d; eS[p] = v;
}

// ---------------- edge-branch gather: o = 0.5 * nbr ----------------
template<int DH>
__global__ __launch_bounds__(256) void gather_kernel(const float* __restrict__ h,
    const int* __restrict__ offsets, const int* __restrict__ dstS,
    const float* __restrict__ eS, const float* __restrict__ denom,
    float* __restrict__ o) {
  constexpr int NC = DH / 64;
  int wid = threadIdx.x >> 6, lane = threadIdx.x & 63;
  int i = blockIdx.x * 4 + wid;
  int beg = offsets[i], end = offsets[i + 1];
  float rd = (beg < end) ? 1.0f / denom[i] : 0.0f;
  float acc[NC] = {};
  for (int k = beg; k < end; ++k) {
    int d = dstS[k];
    float a = eS[k] * rd;
    #pragma unroll
    for (int c = 0; c < NC; ++c)
      acc[c] = fmaf(a, h[(size_t)d * DH + c * 64 + lane], acc[c]);
  }
  #pragma unroll
  for (int c = 0; c < NC; ++c)
    o[(size_t)i * DH + c * 64 + lane] = 0.5f * acc[c];
}

// ---------------- fused dense attention: o += h + 0.5*(colsum + Delta@h) ----------------
template<int DH, int JSPLIT>
__global__ __launch_bounds__(256, 2) void dense_kernel(const float* __restrict__ h,
    const float* __restrict__ al, const float* __restrict__ ar,
    const float* __restrict__ inv, const float* __restrict__ cs,
    const float* __restrict__ ab, float* __restrict__ o) {
  constexpr int NKC = DH / 64;
  __shared__ float AT[64][68];   // [k][r]  Hi chunk, transposed
  __shared__ float BT[64][68];   // [k][j]  Hj chunk, transposed
  __shared__ float WR[64][68];   // [r][j]  Delta tile
  __shared__ int sflag;
  int i0 = blockIdx.x * 64;
  int js = blockIdx.y;
  int t = threadIdx.x, ty = t >> 4, tx = t & 15;
  float abv = ab[0];
  float acc[4][4 * NKC] = {};
  float ali[4], invi[4];
  #pragma unroll
  for (int q = 0; q < 4; ++q) { ali[q] = al[i0 + 4 * ty + q]; invi[q] = inv[i0 + 4 * ty + q]; }
  constexpr int TILES = (NN / 64) / JSPLIT;

  for (int jt = 0; jt < TILES; ++jt) {
    int j0 = (js * TILES + jt) * 64;
    if (t == 0) sflag = 0;
    float G[4][4] = {};
    for (int c = 0; c < NKC; ++c) {
      __syncthreads();
      #pragma unroll
      for (int rnd = 0; rnd < 4; ++rnd) {
        int e = rnd * 256 + t;
        int r = e >> 4;
        int k0 = (e & 15) << 2;
        float4 va = *(const float4*)&h[(size_t)(i0 + r) * DH + c * 64 + k0];
        float4 vb = *(const float4*)&h[(size_t)(j0 + r) * DH + c * 64 + k0];
        AT[k0 + 0][r] = va.x; AT[k0 + 1][r] = va.y; AT[k0 + 2][r] = va.z; AT[k0 + 3][r] = va.w;
        BT[k0 + 0][r] = vb.x; BT[k0 + 1][r] = vb.y; BT[k0 + 2][r] = vb.z; BT[k0 + 3][r] = vb.w;
      }
      __syncthreads();
      for (int k = 0; k < 64; ++k) {
        float4 a4 = *(const float4*)&AT[k][4 * ty];
        float4 b4 = *(const float4*)&BT[k][4 * tx];
        float a[4] = {a4.x, a4.y, a4.z, a4.w};
        float b[4] = {b4.x, b4.y, b4.z, b4.w};
        #pragma unroll
        for (int q = 0; q < 4; ++q)
          #pragma unroll
          for (int p = 0; p < 4; ++p) G[q][p] = fmaf(a[q], b[p], G[q][p]);
      }
    }
    // phase B: transform G -> Delta weights
    float arj[4], invj[4];
    #pragma unroll
    for (int p = 0; p < 4; ++p) { arj[p] = ar[j0 + 4 * tx + p]; invj[p] = inv[j0 + 4 * tx + p]; }
    int lany = 0;
    float w[4][4];
    #pragma unroll
    for (int q = 0; q < 4; ++q)
      #pragma unroll
      for (int p = 0; p < 4; ++p) {
        float C = G[q][p] * invi[q] * invj[p];
        float wv = 0.0f;
        if (C > 0.36f) { lany = 1; wv = expm1f(C * lrelu_f(ali[q] + arj[p] + abv)); }
        w[q][p] = wv;
      }
    if (lany) atomicOr(&sflag, 1);
    #pragma unroll
    for (int q = 0; q < 4; ++q)
      *(float4*)&WR[4 * ty + q][4 * tx] = make_float4(w[q][0], w[q][1], w[q][2], w[q][3]);
    __syncthreads();
    int active = sflag;
    if (active) {
      for (int c = 0; c < NKC; ++c) {
        __syncthreads();
        #pragma unroll
        for (int rnd = 0; rnd < 4; ++rnd) {
          int e = rnd * 256 + t;
          int r = e >> 4;
          int k0 = (e & 15) << 2;
          float4 vb = *(const float4*)&h[(size_t)(j0 + r) * DH + c * 64 + k0];
          BT[k0 + 0][r] = vb.x; BT[k0 + 1][r] = vb.y; BT[k0 + 2][r] = vb.z; BT[k0 + 3][r] = vb.w;
        }
        __syncthreads();
        for (int jj = 0; jj < 64; jj += 4) {
          float4 wv[4], hv[4];
          #pragma unroll
          for (int q = 0; q < 4; ++q) wv[q] = *(const float4*)&WR[4 * ty + q][jj];
          #pragma unroll
          for (int p = 0; p < 4; ++p) hv[p] = *(const float4*)&BT[tx + 16 * p][jj];
          #pragma unroll
          for (int q = 0; q < 4; ++q)
            #pragma unroll
            for (int p = 0; p < 4; ++p) {
              acc[q][4 * c + p] = fmaf(wv[q].x, hv[p].x, acc[q][4 * c + p]);
              acc[q][4 * c + p] = fmaf(wv[q].y, hv[p].y, acc[q][4 * c + p]);
              acc[q][4 * c + p] = fmaf(wv[q].z, hv[p].z, acc[q][4 * c + p]);
              acc[q][4 * c + p] = fmaf(wv[q].w, hv[p].w, acc[q][4 * c + p]);
            }
        }
      }
    }
  }
  // epilogue
  #pragma unroll
  for (int q = 0; q < 4; ++q) {
    int i = i0 + 4 * ty + q;
    #pragma unroll
    for (int c = 0; c < NKC; ++c)
      #pragma unroll
      for (int p = 0; p < 4; ++p) {
        int d = c * 64 + tx + 16 * p;
        float add = 0.5f * acc[q][4 * c + p];
        if (js == 0) add += h[(size_t)i * DH + d] + 0.5f * cs[d];
        atomicAdd(&o[(size_t)i * DH + d], add);
      }
  }
}

// ---------------- final row-normalize (in place on d_out) ----------------
__global__ __launch_bounds__(256) void norm_kernel(float* __restrict__ out) {
  int wid = threadIdx.x >> 6, lane = threadIdx.x & 63;
  int i = blockIdx.x * 4 + wid;
  float x = out[(size_t)i * 64 + lane];
  float s = x * x;
  #pragma unroll
  for (int m = 32; m > 0; m >>= 1) s += __shfl_xor(s, m);
  float n = sqrtf(s);
  out[(size_t)i * 64 + lane] = x / fmaxf(n, 1e-12f);
}

// ---------------- host-side orchestration ----------------
struct Scratch {
  float *al, *ar, *inv, *denom, *cs, *eS;
  int *counts, *offsets, *cursor, *dstS;
};

template<int DH>
static void run_attention(const float* h, const float* aw, const float* ab, float* o,
                          const int* src, const int* dst, const Scratch& S, hipStream_t stream) {
  rowstats_kernel<DH><<<NN / 4, 256, 0, stream>>>(h, aw, S.al, S.ar, S.inv);
  hipMemsetAsync(S.cs, 0, DH * sizeof(float), stream);
  colsum_kernel<DH><<<32, DH, 0, stream>>>(h, S.cs);
  hipMemsetAsync(S.counts, 0, NN * sizeof(int), stream);
  hist_kernel<<<NE / 256, 256, 0, stream>>>(src, S.counts);
  scan_kernel<<<1, 1024, 0, stream>>>(S.counts, S.offsets, S.cursor);
  hipMemsetAsync(S.denom, 0, NN * sizeof(float), stream);
  scatter_kernel<<<NE / 256, 256, 0, stream>>>(src, dst, S.al, S.ar, ab,
                                               S.denom, S.cursor, S.dstS, S.eS);
  gather_kernel<DH><<<NN / 4, 256, 0, stream>>>(h, S.offsets, S.dstS, S.eS, S.denom, o);
  dense_kernel<DH, 8><<<dim3(NN / 64, 8), 256, 0, stream>>>(h, S.al, S.ar, S.inv, S.cs, ab, o);
}

extern "C" void kernel_launch(void* const* d_in, const int* in_sizes, int n_in,
                              void* d_out, int out_size, void* d_ws, size_t ws_size,
                              hipStream_t stream) {
  const float* X   = (const float*)d_in[0];
  const int*   ei  = (const int*)d_in[1];
  const float* W1  = (const float*)d_in[2];
  const float* b1  = (const float*)d_in[3];
  const float* a1w = (const float*)d_in[4];
  const float* a1b = (const float*)d_in[5];
  const float* W2  = (const float*)d_in[6];
  const float* b2  = (const float*)d_in[7];
  const float* a2w = (const float*)d_in[8];
  const float* a2b = (const float*)d_in[9];
  const float* W3  = (const float*)d_in[10];
  const float* b3  = (const float*)d_in[11];
  float* out = (float*)d_out;

  const int* src = ei;
  const int* dst = ei + NE;

  float* fws = (float*)d_ws;
  float* h1 = fws;                 // 4096*256
  float* o1 = h1 + 1048576;        // 4096*256
  float* h2 = o1 + 1048576;        // 4096*128
  float* o2 = h2 + 524288;         // 4096*128
  Scratch S;
  S.al    = o2 + 524288;
  S.ar    = S.al + NN;
  S.inv   = S.ar + NN;
  S.denom = S.inv + NN;
  S.cs    = S.denom + NN;          // 256 max
  S.eS    = S.cs + 256;            // NE
  S.counts  = (int*)(S.eS + NE);   // NN
  S.offsets = S.counts + NN;       // NN+1
  S.cursor  = S.offsets + NN + 1;  // NN
  S.dstS    = S.cursor + NN;       // NE

  // layer 1
  gemm_kernel<false><<<dim3(NN / 64, 256 / 64), 256, 0, stream>>>(X, W1, b1, h1, 128, 256);
  run_attention<256>(h1, a1w, a1b, o1, src, dst, S, stream);
  // layer 2
  gemm_kernel<true><<<dim3(NN / 64, 128 / 64), 256, 0, stream>>>(o1, W2, b2, h2, 256, 128);
  run_attention<128>(h2, a2w, a2b, o2, src, dst, S, stream);
  // output layer + normalize
  gemm_kernel<true><<<dim3(NN / 64, 64 / 64), 256, 0, stream>>>(o2, W3, b3, out, 128, 64);
  norm_kernel<<<NN / 4, 256, 0, stream>>>(out);
}